// Round 1
// baseline (239.359 us; speedup 1.0000x reference)
//
#include <hip/hip_runtime.h>

// Problem constants (fixed by the reference):
#define B_ 8
#define S_ 8192
#define H_ 512
#define D_ 768
#define P_ 128

// ---------------------------------------------------------------------------
// Kernel 1: per-(b,p) mean pooling.
// patch_ids are sorted ascending within each batch row, so the rows belonging
// to patch p form a CONTIGUOUS slab [start, end) found by binary search.
// Grid (P_, B_), 256 threads/block. Thread t owns columns {2t, 2t+1} (float2),
// so each wave reads a contiguous 512B chunk per row -> fully coalesced.
// ---------------------------------------------------------------------------
__global__ __launch_bounds__(256) void pool_kernel(
    const float* __restrict__ bh, const int* __restrict__ ids,
    float* __restrict__ means)
{
    const int p = blockIdx.x;
    const int b = blockIdx.y;
    const int t = threadIdx.x;
    const int* row = ids + (size_t)b * S_;

    // lower_bound(row, p): first index with row[i] >= p
    int lo = 0, hi = S_;
    while (lo < hi) { int mid = (lo + hi) >> 1; if (row[mid] < p) lo = mid + 1; else hi = mid; }
    const int start = lo;
    // lower_bound(row, p+1), searching only [start, S)
    hi = S_;
    while (lo < hi) { int mid = (lo + hi) >> 1; if (row[mid] <= p) lo = mid + 1; else hi = mid; }
    const int end = lo;
    const int cnt = end - start;

    // Contiguous slab: bh[b, start:end, :]. Two accumulators for 2-row ILP.
    const float2* src = (const float2*)(bh + ((size_t)b * S_ + (size_t)start) * H_) + t;
    float ax0 = 0.f, ay0 = 0.f, ax1 = 0.f, ay1 = 0.f;
    int r = 0;
    for (; r + 2 <= cnt; r += 2) {
        float2 v0 = src[(size_t)r * (H_ / 2)];
        float2 v1 = src[(size_t)(r + 1) * (H_ / 2)];
        ax0 += v0.x; ay0 += v0.y;
        ax1 += v1.x; ay1 += v1.y;
    }
    if (r < cnt) {
        float2 v = src[(size_t)r * (H_ / 2)];
        ax0 += v.x; ay0 += v.y;
    }
    const float inv = 1.0f / (float)(cnt > 0 ? cnt : 1);
    float2 o;
    o.x = (ax0 + ax1) * inv;
    o.y = (ay0 + ay1) * inv;
    ((float2*)(means + ((size_t)(b * P_ + p)) * H_))[t] = o;
}

// ---------------------------------------------------------------------------
// Kernel 2: C[M=1024, N=768] = A[1024,512] @ W[512,768] + bias.
// fp32 (no fp32-input MFMA on CDNA4 -> vector ALU).
// 256 threads as 16x16; 64x64 output tile; 4x4 microtile/thread; BK=16.
// As padded to stride 68 words: keeps As[k][4*ty] 16B-aligned for
// ds_read_b128 and gives <=2-way bank aliasing on staging writes (free).
// ---------------------------------------------------------------------------
__global__ __launch_bounds__(256) void gemm_kernel(
    const float* __restrict__ A, const float* __restrict__ W,
    const float* __restrict__ bias, float* __restrict__ C)
{
    const int K = H_, N = D_;
    __shared__ float As[16][68];  // [k][m], padded
    __shared__ float Bs[16][64];  // [k][n]

    const int t  = threadIdx.x;
    const int tx = t & 15;        // n-direction
    const int ty = t >> 4;        // m-direction
    const int m0 = blockIdx.y * 64;
    const int n0 = blockIdx.x * 64;

    float acc[4][4] = {};

    for (int k0 = 0; k0 < K; k0 += 16) {
        // Stage A tile (64 rows x 16 k). idx layout: consecutive t covers
        // consecutive k within a row -> 64B-segment coalesced loads.
        #pragma unroll
        for (int i = 0; i < 4; ++i) {
            int idx = t + i * 256;
            int m = idx >> 4, k = idx & 15;
            As[k][m] = A[(size_t)(m0 + m) * K + (k0 + k)];
        }
        // Stage B tile (16 k x 64 n): consecutive t -> consecutive n, coalesced.
        #pragma unroll
        for (int i = 0; i < 4; ++i) {
            int idx = t + i * 256;
            int k = idx >> 6, n = idx & 63;
            Bs[k][n] = W[(size_t)(k0 + k) * N + (n0 + n)];
        }
        __syncthreads();

        #pragma unroll
        for (int k = 0; k < 16; ++k) {
            float4 a4 = *(const float4*)&As[k][ty * 4];
            float4 b4 = *(const float4*)&Bs[k][tx * 4];
            const float a[4] = {a4.x, a4.y, a4.z, a4.w};
            const float bb[4] = {b4.x, b4.y, b4.z, b4.w};
            #pragma unroll
            for (int i = 0; i < 4; ++i)
                #pragma unroll
                for (int j = 0; j < 4; ++j)
                    acc[i][j] += a[i] * bb[j];
        }
        __syncthreads();
    }

    #pragma unroll
    for (int i = 0; i < 4; ++i) {
        const int m = m0 + ty * 4 + i;
        #pragma unroll
        for (int j = 0; j < 4; ++j) {
            const int n = n0 + tx * 4 + j;
            C[(size_t)m * N + n] = acc[i][j] + bias[n];
        }
    }
}

extern "C" void kernel_launch(void* const* d_in, const int* in_sizes, int n_in,
                              void* d_out, int out_size, void* d_ws, size_t ws_size,
                              hipStream_t stream) {
    // setup_inputs order: byte_hiddens (f32), W_proj (f32), b_proj (f32), patch_ids (i32)
    const float* bh   = (const float*)d_in[0];
    const float* W    = (const float*)d_in[1];
    const float* bias = (const float*)d_in[2];
    const int*   ids  = (const int*)d_in[3];
    float* out   = (float*)d_out;
    float* means = (float*)d_ws;  // B*P*H floats = 2 MiB scratch

    dim3 g1(P_, B_);
    pool_kernel<<<g1, 256, 0, stream>>>(bh, ids, means);

    dim3 g2(D_ / 64, (B_ * P_) / 64);  // (12, 16)
    gemm_kernel<<<g2, 256, 0, stream>>>(means, W, bias, out);
}

// Round 2
// 229.091 us; speedup vs baseline: 1.0448x; 1.0448x over previous
//
#include <hip/hip_runtime.h>

// Problem constants (fixed by the reference):
#define B_ 8
#define S_ 8192
#define H_ 512
#define D_ 768
#define P_ 128

// ---------------------------------------------------------------------------
// Kernel 0: segment bounds. patch_ids sorted per batch row, so segment p is
// [lower_bound(p), lower_bound(p+1)). 8 blocks x 128 threads; thread p does a
// 13-step binary search (S=2^13). All searches run in parallel, removing the
// 26-dependent-load serial prefix from every one of the 1024 pool blocks.
// bounds[b][p] = lower_bound(p); bounds[b][P] = S (sentinel) => end = next start.
// ---------------------------------------------------------------------------
__global__ __launch_bounds__(128) void bounds_kernel(
    const int* __restrict__ ids, int* __restrict__ bounds)
{
    const int b = blockIdx.x;
    const int p = threadIdx.x;  // 0..127
    const int* row = ids + (size_t)b * S_;
    int lo = 0, hi = S_;
    #pragma unroll 13
    while (lo < hi) { int mid = (lo + hi) >> 1; if (row[mid] < p) lo = mid + 1; else hi = mid; }
    bounds[b * (P_ + 1) + p] = lo;
    if (p == 0) bounds[b * (P_ + 1) + P_] = S_;
}

// ---------------------------------------------------------------------------
// Kernel 1: per-(b,p) mean over a contiguous slab. Grid (P,B), 256 threads.
// float4 columns: c = t&127 covers the 512-float row; r_ofs = t>>7 splits rows
// across two half-blocks. Unroll-2 => 4 rows (8 KB) in flight per block,
// 4 blocks/CU => 32 KB in flight/CU (> ~9 KB needed to saturate HBM).
// Cross-half combine via 2 KB LDS.
// ---------------------------------------------------------------------------
__global__ __launch_bounds__(256) void pool_kernel(
    const float* __restrict__ bh, const int* __restrict__ bounds,
    float* __restrict__ means)
{
    const int p = blockIdx.x;
    const int b = blockIdx.y;
    const int t = threadIdx.x;
    const int c = t & 127;      // float4 column
    const int r_ofs = t >> 7;   // 0 or 1

    const int start = bounds[b * (P_ + 1) + p];      // wave-uniform -> s_load
    const int end   = bounds[b * (P_ + 1) + p + 1];
    const int cnt   = end - start;

    const float4* src = (const float4*)(bh + ((size_t)b * S_ + (size_t)start) * H_) + c;
    float4 a0 = {0.f, 0.f, 0.f, 0.f};
    float4 a1 = {0.f, 0.f, 0.f, 0.f};

    int r = r_ofs;
    for (; r + 2 < cnt; r += 4) {
        float4 v0 = src[(size_t)r * (H_ / 4)];
        float4 v1 = src[(size_t)(r + 2) * (H_ / 4)];
        a0.x += v0.x; a0.y += v0.y; a0.z += v0.z; a0.w += v0.w;
        a1.x += v1.x; a1.y += v1.y; a1.z += v1.z; a1.w += v1.w;
    }
    if (r < cnt) {
        float4 v = src[(size_t)r * (H_ / 4)];
        a0.x += v.x; a0.y += v.y; a0.z += v.z; a0.w += v.w;
    }
    float4 s;
    s.x = a0.x + a1.x; s.y = a0.y + a1.y; s.z = a0.z + a1.z; s.w = a0.w + a1.w;

    __shared__ float4 red[128];
    if (r_ofs == 1) red[c] = s;
    __syncthreads();
    if (r_ofs == 0) {
        float4 o = red[c];
        const float inv = 1.0f / (float)(cnt > 0 ? cnt : 1);
        float4 out;
        out.x = (s.x + o.x) * inv; out.y = (s.y + o.y) * inv;
        out.z = (s.z + o.z) * inv; out.w = (s.w + o.w) * inv;
        ((float4*)(means + ((size_t)(b * P_ + p)) * H_))[c] = out;
    }
}

// ---------------------------------------------------------------------------
// Kernel 2: C[1024,768] = A[1024,512] @ W[512,768] + bias (fp32 vector ALU —
// no fp32-input MFMA on CDNA4). 64x64 tile, 256 threads, 4x4 microtile, BK=16.
// Register prefetch of the NEXT tile's global data is issued right after the
// staging barrier, so the ~200-900 cyc load latency hides behind the 512
// FMA-cycles of the current tile — critical at 1 block/CU (192 blocks).
// ---------------------------------------------------------------------------
__global__ __launch_bounds__(256) void gemm_kernel(
    const float* __restrict__ A, const float* __restrict__ W,
    const float* __restrict__ bias, float* __restrict__ C)
{
    const int K = H_, N = D_;
    __shared__ float As[16][68];  // [k][m], +4 pad keeps ds_read_b128 aligned, <=2-way banks (free)
    __shared__ float Bs[16][64];  // [k][n]

    const int t  = threadIdx.x;
    const int tx = t & 15;        // n
    const int ty = t >> 4;        // m
    const int m0 = blockIdx.y * 64;
    const int n0 = blockIdx.x * 64;

    // Staging maps (float4 global loads):
    const int am = t >> 2;          // 0..63   A row
    const int ak = (t & 3) * 4;     // 0,4,8,12
    const int bk = t >> 4;          // 0..15   W row (k)
    const int bn = (t & 15) * 4;    // 0..60
    const float* Aptr = A + (size_t)(m0 + am) * K + ak;
    const float* Wptr = W + (size_t)bk * N + (n0 + bn);

    float4 a_reg = *(const float4*)Aptr;
    float4 b_reg = *(const float4*)Wptr;

    float acc[4][4] = {};

    for (int k0 = 0; k0 < K; k0 += 16) {
        As[ak + 0][am] = a_reg.x;
        As[ak + 1][am] = a_reg.y;
        As[ak + 2][am] = a_reg.z;
        As[ak + 3][am] = a_reg.w;
        *(float4*)&Bs[bk][bn] = b_reg;
        __syncthreads();

        if (k0 + 16 < K) {  // prefetch next tile while we compute this one
            a_reg = *(const float4*)(Aptr + (k0 + 16));
            b_reg = *(const float4*)(Wptr + (size_t)(k0 + 16) * N);
        }

        #pragma unroll
        for (int k = 0; k < 16; ++k) {
            float4 a4 = *(const float4*)&As[k][ty * 4];
            float4 b4 = *(const float4*)&Bs[k][tx * 4];
            const float a[4] = {a4.x, a4.y, a4.z, a4.w};
            const float bb[4] = {b4.x, b4.y, b4.z, b4.w};
            #pragma unroll
            for (int i = 0; i < 4; ++i)
                #pragma unroll
                for (int j = 0; j < 4; ++j)
                    acc[i][j] += a[i] * bb[j];
        }
        __syncthreads();
    }

    const float4 bv = *(const float4*)&bias[n0 + tx * 4];
    const float badd[4] = {bv.x, bv.y, bv.z, bv.w};
    #pragma unroll
    for (int i = 0; i < 4; ++i) {
        const int m = m0 + ty * 4 + i;
        float4 o;
        o.x = acc[i][0] + badd[0];
        o.y = acc[i][1] + badd[1];
        o.z = acc[i][2] + badd[2];
        o.w = acc[i][3] + badd[3];
        *(float4*)&C[(size_t)m * N + n0 + tx * 4] = o;
    }
}

extern "C" void kernel_launch(void* const* d_in, const int* in_sizes, int n_in,
                              void* d_out, int out_size, void* d_ws, size_t ws_size,
                              hipStream_t stream) {
    const float* bh   = (const float*)d_in[0];
    const float* W    = (const float*)d_in[1];
    const float* bias = (const float*)d_in[2];
    const int*   ids  = (const int*)d_in[3];
    float* out   = (float*)d_out;
    float* means = (float*)d_ws;                         // B*P*H floats = 2 MiB
    int*   bounds = (int*)(means + (size_t)B_ * P_ * H_); // B*(P+1) ints

    bounds_kernel<<<dim3(B_), 128, 0, stream>>>(ids, bounds);

    dim3 g1(P_, B_);
    pool_kernel<<<g1, 256, 0, stream>>>(bh, bounds, means);

    dim3 g2(D_ / 64, (B_ * P_) / 64);  // (12, 16)
    gemm_kernel<<<g2, 256, 0, stream>>>(means, W, bias, out);
}

// Round 3
// 210.240 us; speedup vs baseline: 1.1385x; 1.0897x over previous
//
#include <hip/hip_runtime.h>

// Problem constants (fixed by the reference):
#define B_ 8
#define S_ 8192
#define H_ 512
#define D_ 768
#define P_ 128

typedef __attribute__((ext_vector_type(8))) short bf16x8;   // 8 bf16 (4 VGPRs)
typedef __attribute__((ext_vector_type(4))) float f32x4;    // MFMA C/D

// fp32 -> bf16 round-to-nearest-even (bit-level, avoids hip_bf16 API variance)
static __device__ inline unsigned short f2bf(float f) {
    unsigned int u = __float_as_uint(f);
    unsigned int r = (u + 0x7fffu + ((u >> 16) & 1u)) >> 16;
    return (unsigned short)r;
}

// ws layout: means_bf16 [B*P][H] (1 MiB) | Wt_bf16 [D][H] (0.75 MiB)

// ---------------------------------------------------------------------------
// Kernel A: W[512][768] fp32 -> Wt_bf16[768][512] (transposed, bf16).
// Needed so GEMM B-fragments (B[k=quad*8+j][n=lane&15]) read 16 contiguous
// bytes. 64x64 tiles via LDS. Tiny: 1.5 MB read, 0.75 MB write (~0.5 us).
// ---------------------------------------------------------------------------
__global__ __launch_bounds__(256) void wt_kernel(
    const float* __restrict__ W, unsigned short* __restrict__ Wt)
{
    const int nb = blockIdx.x * 64;  // n (col of W) tile base
    const int kb = blockIdx.y * 64;  // k (row of W) tile base
    __shared__ unsigned short T[64][72];  // [n][k], padded
    const int t = threadIdx.x;
    {
        const int kk = t >> 4;         // 0..15
        const int nn = (t & 15) * 4;   // 0..60
        #pragma unroll
        for (int i = 0; i < 4; ++i) {
            float4 v = *(const float4*)&W[(size_t)(kb + kk + i * 16) * D_ + nb + nn];
            T[nn + 0][kk + i * 16] = f2bf(v.x);
            T[nn + 1][kk + i * 16] = f2bf(v.y);
            T[nn + 2][kk + i * 16] = f2bf(v.z);
            T[nn + 3][kk + i * 16] = f2bf(v.w);
        }
    }
    __syncthreads();
    {
        const int nn = t >> 4;         // 0..15
        const int kk = (t & 15) * 4;   // 0..60
        #pragma unroll
        for (int i = 0; i < 4; ++i) {
            ushort4 o;
            o.x = T[nn + i * 16][kk + 0];
            o.y = T[nn + i * 16][kk + 1];
            o.z = T[nn + i * 16][kk + 2];
            o.w = T[nn + i * 16][kk + 3];
            *(ushort4*)&Wt[(size_t)(nb + nn + i * 16) * H_ + kb + kk] = o;
        }
    }
}

// ---------------------------------------------------------------------------
// Kernel B: per-(b,p) mean over a contiguous slab (ids sorted per row).
// Bounds fused: two INTERLEAVED 13-step binary searches (independent dep
// chains, wave-uniform -> scalarized) replace the separate bounds kernel.
// 256 threads: c=t&127 covers the 512-float row as float4; halves split rows
// by parity; unroll-2 => 4 rows (8 KB) in flight/block, 4 blocks/CU.
// Writes bf16 means (GEMM input) — halves means traffic.
// ---------------------------------------------------------------------------
__global__ __launch_bounds__(256) void pool_kernel(
    const float* __restrict__ bh, const int* __restrict__ ids,
    unsigned short* __restrict__ means)
{
    const int p = blockIdx.x;
    const int b = blockIdx.y;
    const int t = threadIdx.x;
    const int c = t & 127;
    const int r_ofs = t >> 7;

    const int* row = ids + (size_t)b * S_;
    int lo0 = 0, hi0 = S_, lo1 = 0, hi1 = S_;
    #pragma unroll
    for (int it = 0; it < 13; ++it) {   // 8192 = 2^13 -> converged
        int m0 = (lo0 + hi0) >> 1, m1 = (lo1 + hi1) >> 1;
        int v0 = row[m0], v1 = row[m1];
        if (v0 < p)  lo0 = m0 + 1; else hi0 = m0;
        if (v1 <= p) lo1 = m1 + 1; else hi1 = m1;
    }
    const int start = lo0;
    const int cnt   = lo1 - lo0;

    const float4* src = (const float4*)(bh + ((size_t)b * S_ + (size_t)start) * H_) + c;
    float4 a0 = {0.f, 0.f, 0.f, 0.f};
    float4 a1 = {0.f, 0.f, 0.f, 0.f};
    int r = r_ofs;
    for (; r + 2 < cnt; r += 4) {
        float4 v0 = src[(size_t)r * (H_ / 4)];
        float4 v1 = src[(size_t)(r + 2) * (H_ / 4)];
        a0.x += v0.x; a0.y += v0.y; a0.z += v0.z; a0.w += v0.w;
        a1.x += v1.x; a1.y += v1.y; a1.z += v1.z; a1.w += v1.w;
    }
    if (r < cnt) {
        float4 v = src[(size_t)r * (H_ / 4)];
        a0.x += v.x; a0.y += v.y; a0.z += v.z; a0.w += v.w;
    }
    float4 s;
    s.x = a0.x + a1.x; s.y = a0.y + a1.y; s.z = a0.z + a1.z; s.w = a0.w + a1.w;

    __shared__ float4 red[128];
    if (r_ofs == 1) red[c] = s;
    __syncthreads();
    if (r_ofs == 0) {
        float4 o = red[c];
        const float inv = 1.0f / (float)(cnt > 0 ? cnt : 1);
        ushort4 w;
        w.x = f2bf((s.x + o.x) * inv);
        w.y = f2bf((s.y + o.y) * inv);
        w.z = f2bf((s.z + o.z) * inv);
        w.w = f2bf((s.w + o.w) * inv);
        *(ushort4*)&means[((size_t)(b * P_ + p)) * H_ + c * 4] = w;
    }
}

// ---------------------------------------------------------------------------
// Kernel C: C[1024,768] = means_bf16 @ Wt_bf16^T + bias, via
// mfma_f32_16x16x32_bf16. 64x64 tile, 256 threads = 4 waves; wave w owns
// rows [w*16, w*16+16), 4 n-tiles of 16. BK=32 -> 16 k-steps, 4 MFMA/step.
// LDS rows padded to 40 halfs (80 B = 5x16B): ds_read_b128-aligned, <=2-way
// bank aliasing (free per m136). Register prefetch hides staging latency
// (1 block/CU -> no co-resident waves to overlap with).
// A-frag: A[m=lane&15][k=quad*8+j]; B-frag: B[k=quad*8+j][n=lane&15];
// C/D: col=lane&15, row=quad*4+reg (verified m89/m91).
// ---------------------------------------------------------------------------
__global__ __launch_bounds__(256) void gemm_kernel(
    const unsigned short* __restrict__ A, const unsigned short* __restrict__ Bt,
    const float* __restrict__ bias, float* __restrict__ C)
{
    __shared__ unsigned short As[64][40];  // [m][k]
    __shared__ unsigned short Bs[64][40];  // [n][k]

    const int t    = threadIdx.x;
    const int lane = t & 63;
    const int wv   = t >> 6;
    const int mrow = lane & 15;
    const int quad = lane >> 4;
    const int m0   = blockIdx.y * 64;
    const int n0   = blockIdx.x * 64;

    // staging map: thread t loads 8 consecutive bf16 (16 B) of row (t>>2)
    const int sr = t >> 2;          // 0..63 (m for A, n for Bt)
    const int sk = (t & 3) * 8;     // 0,8,16,24
    const unsigned short* Aptr = A  + (size_t)(m0 + sr) * H_ + sk;
    const unsigned short* Bptr = Bt + (size_t)(n0 + sr) * H_ + sk;

    uint4 a_reg = *(const uint4*)Aptr;
    uint4 b_reg = *(const uint4*)Bptr;

    f32x4 acc[4] = {};

    for (int k0 = 0; k0 < H_; k0 += 32) {
        *(uint4*)&As[sr][sk] = a_reg;
        *(uint4*)&Bs[sr][sk] = b_reg;
        __syncthreads();

        if (k0 + 32 < H_) {  // prefetch next K-tile during compute
            a_reg = *(const uint4*)(Aptr + k0 + 32);
            b_reg = *(const uint4*)(Bptr + k0 + 32);
        }

        #pragma unroll
        for (int kk = 0; kk < 2; ++kk) {  // two 16x16x32 MFMAs worth of k? no: quad covers 32 k per call
            // quad*8 spans k=0..31 in one call; loop kk unused -> single step
        }
        {
            bf16x8 af = *(const bf16x8*)&As[wv * 16 + mrow][quad * 8];
            #pragma unroll
            for (int t4 = 0; t4 < 4; ++t4) {
                bf16x8 bf = *(const bf16x8*)&Bs[t4 * 16 + mrow][quad * 8];
                acc[t4] = __builtin_amdgcn_mfma_f32_16x16x32_bf16(af, bf, acc[t4], 0, 0, 0);
            }
        }
        __syncthreads();
    }

    #pragma unroll
    for (int t4 = 0; t4 < 4; ++t4) {
        const int col = n0 + t4 * 16 + mrow;
        const float bia = bias[col];
        #pragma unroll
        for (int r = 0; r < 4; ++r) {
            const int rowi = m0 + wv * 16 + quad * 4 + r;
            C[(size_t)rowi * D_ + col] = acc[t4][r] + bia;
        }
    }
}

extern "C" void kernel_launch(void* const* d_in, const int* in_sizes, int n_in,
                              void* d_out, int out_size, void* d_ws, size_t ws_size,
                              hipStream_t stream) {
    const float* bh   = (const float*)d_in[0];
    const float* W    = (const float*)d_in[1];
    const float* bias = (const float*)d_in[2];
    const int*   ids  = (const int*)d_in[3];
    float* out = (float*)d_out;

    unsigned short* means = (unsigned short*)d_ws;                    // 1 MiB
    unsigned short* Wt    = means + (size_t)B_ * P_ * H_;             // 0.75 MiB

    wt_kernel<<<dim3(D_ / 64, H_ / 64), 256, 0, stream>>>(W, Wt);     // (12, 8)
    pool_kernel<<<dim3(P_, B_), 256, 0, stream>>>(bh, ids, means);    // (128, 8)
    gemm_kernel<<<dim3(D_ / 64, (B_ * P_) / 64), 256, 0, stream>>>(   // (12, 16)
        means, Wt, bias, out);
}

// Round 4
// 207.414 us; speedup vs baseline: 1.1540x; 1.0136x over previous
//
#include <hip/hip_runtime.h>

// Problem constants (fixed by the reference):
#define B_ 8
#define S_ 8192
#define H_ 512
#define D_ 768
#define P_ 128

typedef __attribute__((ext_vector_type(8))) short bf16x8;   // 8 bf16 (4 VGPRs)
typedef __attribute__((ext_vector_type(4))) float f32x4;    // MFMA C/D

// fp32 -> bf16 round-to-nearest-even
static __device__ inline unsigned short f2bf(float f) {
    unsigned int u = __float_as_uint(f);
    unsigned int r = (u + 0x7fffu + ((u >> 16) & 1u)) >> 16;
    return (unsigned short)r;
}

// ws layout: means_bf16 [B*P][H] (1 MiB) | Wt_bf16 [D][H] (0.75 MiB)

// ---------------------------------------------------------------------------
// Fused kernel 1: blocks [0,1024) do per-(b,p) mean pooling; blocks
// [1024,1120) transpose+convert W[512][768] fp32 -> Wt_bf16[768][512].
// The two jobs are independent; fusing removes one kernel-launch boundary.
// Pool blocks come FIRST so the long pole (128 MiB HBM read) dispatches first.
//
// Pool: ids sorted per row -> segment p is [lb(p), lb(p+1)); two interleaved
// 13-step binary searches (wave-uniform -> scalarized). float4 columns,
// halves split rows by parity, unroll-2 => 8 KB in flight/block.
// ---------------------------------------------------------------------------
__global__ __launch_bounds__(256) void pool_wt_kernel(
    const float* __restrict__ bh, const int* __restrict__ ids,
    const float* __restrict__ W,
    unsigned short* __restrict__ means, unsigned short* __restrict__ Wt)
{
    __shared__ __align__(16) char smem[64 * 72 * sizeof(unsigned short)];
    const int bid = blockIdx.x;
    const int t = threadIdx.x;

    if (bid < P_ * B_) {
        // ---------------- pool ----------------
        const int p = bid & (P_ - 1);
        const int b = bid >> 7;
        const int c = t & 127;
        const int r_ofs = t >> 7;

        const int* row = ids + (size_t)b * S_;
        int lo0 = 0, hi0 = S_, lo1 = 0, hi1 = S_;
        #pragma unroll
        for (int it = 0; it < 13; ++it) {
            int m0 = (lo0 + hi0) >> 1, m1 = (lo1 + hi1) >> 1;
            int v0 = row[m0], v1 = row[m1];
            if (v0 < p)  lo0 = m0 + 1; else hi0 = m0;
            if (v1 <= p) lo1 = m1 + 1; else hi1 = m1;
        }
        const int start = lo0;
        const int cnt   = lo1 - lo0;

        const float4* src = (const float4*)(bh + ((size_t)b * S_ + (size_t)start) * H_) + c;
        float4 a0 = {0.f, 0.f, 0.f, 0.f};
        float4 a1 = {0.f, 0.f, 0.f, 0.f};
        int r = r_ofs;
        for (; r + 2 < cnt; r += 4) {
            float4 v0 = src[(size_t)r * (H_ / 4)];
            float4 v1 = src[(size_t)(r + 2) * (H_ / 4)];
            a0.x += v0.x; a0.y += v0.y; a0.z += v0.z; a0.w += v0.w;
            a1.x += v1.x; a1.y += v1.y; a1.z += v1.z; a1.w += v1.w;
        }
        if (r < cnt) {
            float4 v = src[(size_t)r * (H_ / 4)];
            a0.x += v.x; a0.y += v.y; a0.z += v.z; a0.w += v.w;
        }
        float4 s;
        s.x = a0.x + a1.x; s.y = a0.y + a1.y; s.z = a0.z + a1.z; s.w = a0.w + a1.w;

        float4* red = (float4*)smem;  // 2 KB
        if (r_ofs == 1) red[c] = s;
        __syncthreads();
        if (r_ofs == 0) {
            float4 o = red[c];
            const float inv = 1.0f / (float)(cnt > 0 ? cnt : 1);
            ushort4 w;
            w.x = f2bf((s.x + o.x) * inv);
            w.y = f2bf((s.y + o.y) * inv);
            w.z = f2bf((s.z + o.z) * inv);
            w.w = f2bf((s.w + o.w) * inv);
            *(ushort4*)&means[((size_t)(b * P_ + p)) * H_ + c * 4] = w;
        }
    } else {
        // ---------------- W transpose+convert ----------------
        const int id = bid - P_ * B_;       // 0..95
        const int nb = (id % (D_ / 64)) * 64;
        const int kb = (id / (D_ / 64)) * 64;
        unsigned short (*T)[72] = (unsigned short (*)[72])smem;  // [n][k]
        {
            const int kk = t >> 4;         // 0..15
            const int nn = (t & 15) * 4;   // 0..60
            #pragma unroll
            for (int i = 0; i < 4; ++i) {
                float4 v = *(const float4*)&W[(size_t)(kb + kk + i * 16) * D_ + nb + nn];
                T[nn + 0][kk + i * 16] = f2bf(v.x);
                T[nn + 1][kk + i * 16] = f2bf(v.y);
                T[nn + 2][kk + i * 16] = f2bf(v.z);
                T[nn + 3][kk + i * 16] = f2bf(v.w);
            }
        }
        __syncthreads();
        {
            const int nn = t >> 4;
            const int kk = (t & 15) * 4;
            #pragma unroll
            for (int i = 0; i < 4; ++i) {
                ushort4 o;
                o.x = T[nn + i * 16][kk + 0];
                o.y = T[nn + i * 16][kk + 1];
                o.z = T[nn + i * 16][kk + 2];
                o.w = T[nn + i * 16][kk + 3];
                *(ushort4*)&Wt[(size_t)(nb + nn + i * 16) * H_ + kb + kk] = o;
            }
        }
    }
}

// ---------------------------------------------------------------------------
// Kernel 2: C[1024,768] = means_bf16 @ Wt_bf16^T + bias via
// mfma_f32_16x16x32_bf16. 64x64 tile, 256 threads = 4 waves; wave w owns rows
// [w*16,w*16+16), 4 n-tiles. BK=64 -> 8 barrier-separated K-steps (halved vs
// BK=32: at 1 block/CU barrier drains are fully exposed, so fewer = faster).
// LDS rows padded to 72 halfs (144 B = 9x16B): ds_read_b128-aligned, <=2-way
// bank aliasing (free, m136). Register prefetch of next K-tile hides global
// load latency behind the 8-MFMA compute phase.
// A-frag: A[m=lane&15][k=quad*8+j]; B-frag: B[k=quad*8+j][n=lane&15];
// C/D: col=lane&15, row=quad*4+reg (verified layouts, m89/m91).
// ---------------------------------------------------------------------------
__global__ __launch_bounds__(256) void gemm_kernel(
    const unsigned short* __restrict__ A, const unsigned short* __restrict__ Bt,
    const float* __restrict__ bias, float* __restrict__ C)
{
    __shared__ unsigned short As[64][72];  // [m][k]
    __shared__ unsigned short Bs[64][72];  // [n][k]

    const int t    = threadIdx.x;
    const int lane = t & 63;
    const int wv   = t >> 6;
    const int mrow = lane & 15;
    const int quad = lane >> 4;
    const int m0   = blockIdx.y * 64;
    const int n0   = blockIdx.x * 64;

    // staging map: thread t loads 32 consecutive bytes (16 bf16) of row t>>2;
    // 4 consecutive threads cover one row's 128 B -> fully coalesced.
    const int sr = t >> 2;
    const int sk = (t & 3) * 16;
    const unsigned short* Aptr = A  + (size_t)(m0 + sr) * H_ + sk;
    const unsigned short* Bptr = Bt + (size_t)(n0 + sr) * H_ + sk;

    uint4 a0 = *(const uint4*)Aptr;
    uint4 a1 = *(const uint4*)(Aptr + 8);
    uint4 b0 = *(const uint4*)Bptr;
    uint4 b1 = *(const uint4*)(Bptr + 8);

    f32x4 acc[4] = {};

    for (int k0 = 0; k0 < H_; k0 += 64) {
        *(uint4*)&As[sr][sk]     = a0;
        *(uint4*)&As[sr][sk + 8] = a1;
        *(uint4*)&Bs[sr][sk]     = b0;
        *(uint4*)&Bs[sr][sk + 8] = b1;
        __syncthreads();

        if (k0 + 64 < H_) {  // prefetch next K-tile during compute
            a0 = *(const uint4*)(Aptr + k0 + 64);
            a1 = *(const uint4*)(Aptr + k0 + 72);
            b0 = *(const uint4*)(Bptr + k0 + 64);
            b1 = *(const uint4*)(Bptr + k0 + 72);
        }

        #pragma unroll
        for (int kk = 0; kk < 2; ++kk) {
            bf16x8 af = *(const bf16x8*)&As[wv * 16 + mrow][kk * 32 + quad * 8];
            #pragma unroll
            for (int t4 = 0; t4 < 4; ++t4) {
                bf16x8 bf = *(const bf16x8*)&Bs[t4 * 16 + mrow][kk * 32 + quad * 8];
                acc[t4] = __builtin_amdgcn_mfma_f32_16x16x32_bf16(af, bf, acc[t4], 0, 0, 0);
            }
        }
        __syncthreads();
    }

    #pragma unroll
    for (int t4 = 0; t4 < 4; ++t4) {
        const int col = n0 + t4 * 16 + mrow;
        const float bia = bias[col];
        #pragma unroll
        for (int r = 0; r < 4; ++r) {
            const int rowi = m0 + wv * 16 + quad * 4 + r;
            C[(size_t)rowi * D_ + col] = acc[t4][r] + bia;
        }
    }
}

extern "C" void kernel_launch(void* const* d_in, const int* in_sizes, int n_in,
                              void* d_out, int out_size, void* d_ws, size_t ws_size,
                              hipStream_t stream) {
    const float* bh   = (const float*)d_in[0];
    const float* W    = (const float*)d_in[1];
    const float* bias = (const float*)d_in[2];
    const int*   ids  = (const int*)d_in[3];
    float* out = (float*)d_out;

    unsigned short* means = (unsigned short*)d_ws;                    // 1 MiB
    unsigned short* Wt    = means + (size_t)B_ * P_ * H_;             // 0.75 MiB

    pool_wt_kernel<<<dim3(P_ * B_ + (D_ / 64) * (H_ / 64)), 256, 0, stream>>>(
        bh, ids, W, means, Wt);                                       // 1120 blocks
    gemm_kernel<<<dim3(D_ / 64, (B_ * P_) / 64), 256, 0, stream>>>(   // (12, 16)
        means, Wt, bias, out);
}